// Round 3
// baseline (380.835 us; speedup 1.0000x reference)
//
#include <hip/hip_runtime.h>
#include <hip/hip_bf16.h>
#include <math.h>

// ---------------------------------------------------------------------------
// MultiHeadSelfAttention  B=4 N=2048 E=512 H=8 DK=DV=64   (f32 in / f32 out)
//
// Internally split-bf16 ("Markidis") MFMA on the attention-critical path:
//   f = hi(trunc bf16) + lo(RNE bf16 of remainder)  ->  ~2^-17 rel residual
//   A*B ~= Ahi*Bhi + Ahi*Blo + Alo*Bhi   (3 MFMAs, lo*lo dropped)
//
// Reference quirks reproduced exactly:
//  * qkv.reshape(B,H,N,192) is a raw reshape (token-mixing):
//      q[b,h,n,d] = qkv[b, 256*h + (n>>3), (n&7)*192 + d]  (k: +64, v: +128)
//    64-col GEMM tiles align with 192-blocks (192 = 3*64): tile tn is purely
//    section tn%3 (0=q,1=k,2=v) of block s = tn/3, with n = 8*a + s.
//  * y.reshape(B,N,512): y[b,h,n,d] -> yws[bh*256 + (n>>3)][(n&7)*64 + d]
//  * qk / DK**-0.5  ==  qk * 8.0
//
// Pipeline:
//   K0 cvtw:  W_qkv -> k-major hi/lo bf16; W_o -> k-major bf16
//   K1 qkv :  split x (regs) @ split Wqkv + bias -> q_hi/lo, k_hi/lo, v  [bh][n][d]
//   K2 attn:  flash attention, 3-term split QK^T, online softmax -> y (bf16)
//   K3 out :  y @ Wo + b_o -> f32 out (plain bf16 MFMA)
// ---------------------------------------------------------------------------

typedef __attribute__((ext_vector_type(8))) short bf16x8;
typedef __attribute__((ext_vector_type(4))) float f32x4;

#define MFMA16(a, b, c) __builtin_amdgcn_mfma_f32_16x16x32_bf16((a), (b), (c), 0, 0, 0)

__device__ __forceinline__ ushort f2bf_rne(float f) {
  union { float f; unsigned u; } v; v.f = f;
  return (ushort)((v.u + 0x7fffu + ((v.u >> 16) & 1u)) >> 16);
}
__device__ __forceinline__ float bf2f(ushort h) {
  union { float f; unsigned u; } v; v.u = ((unsigned)h) << 16; return v.f;
}
// hi = truncated-bf16 prefix (exact subtraction), lo = RNE(f - hi)
__device__ __forceinline__ void split2(float f, ushort& hi, ushort& lo) {
  union { float f; unsigned u; } v; v.f = f;
  hi = (ushort)(v.u >> 16);
  lo = f2bf_rne(f - bf2f(hi));
}

// ---------------------------------------------------------------------------
// K0: W_qkv (512x1536 f32) -> wT_hi/wT_lo (1536x512 bf16, k-major)
//     W_o   (512x512  f32) -> woT (512x512 bf16, k-major)
// ---------------------------------------------------------------------------
__global__ __launch_bounds__(256) void cvtw_k(const float* __restrict__ wqkv,
                                              const float* __restrict__ wo,
                                              ushort* __restrict__ wT_hi,
                                              ushort* __restrict__ wT_lo,
                                              ushort* __restrict__ woT)
{
  const int gid = blockIdx.x * 256 + threadIdx.x;   // 1048576 total
  if (gid < 786432) {
    const int n = gid >> 9, k = gid & 511;
    ushort hi, lo; split2(wqkv[(size_t)k * 1536 + n], hi, lo);
    wT_hi[gid] = hi; wT_lo[gid] = lo;
  } else {
    const int g = gid - 786432;
    const int n = g >> 9, k = g & 511;
    woT[g] = f2bf_rne(wo[(size_t)k * 512 + n]);
  }
}

// ---------------------------------------------------------------------------
// K1: qkv GEMM, 64x64 tile per block (4 waves, wave = 16 rows x 64 cols).
// A = x f32 read directly to registers, split hi/lo. B = wT hi/lo via LDS.
// Epilogue applies the reshape permutation; q,k stored split, v plain bf16.
// Grid: 128 row-blocks x 24 col-blocks = 3072.
// ---------------------------------------------------------------------------
__global__ __launch_bounds__(256) void qkv_gemm_k(
    const float* __restrict__ x, const ushort* __restrict__ wT_hi,
    const ushort* __restrict__ wT_lo, const float* __restrict__ bqkv,
    ushort* __restrict__ q_hi, ushort* __restrict__ q_lo,
    ushort* __restrict__ k_hi, ushort* __restrict__ k_lo,
    ushort* __restrict__ v_arr)
{
  const int tmb = blockIdx.x / 24;
  const int tn  = blockIdx.x % 24;
  const int tid = threadIdx.x, lane = tid & 63, w = tid >> 6;
  const int col16 = lane & 15, quad = lane >> 4;

  __shared__ short bh_lds[64][40];   // [n][k] hi, 80B rows (16B-aligned)
  __shared__ short bl_lds[64][40];   // [n][k] lo

  // B stager: thread -> (n, k-segment)
  const int sn = tid >> 2, sseg = tid & 3;
  const ushort* bh_src = wT_hi + ((size_t)(tn * 64 + sn)) * 512 + sseg * 8;
  const ushort* bl_src = wT_lo + ((size_t)(tn * 64 + sn)) * 512 + sseg * 8;

  // A: direct f32 from x (each wave owns 16 distinct rows)
  const int arow = tmb * 64 + w * 16 + col16;
  const float* ax = x + (size_t)arow * 512 + quad * 8;

  f32x4 acc[4];
#pragma unroll
  for (int ct = 0; ct < 4; ++ct) acc[ct] = (f32x4){0.f, 0.f, 0.f, 0.f};

  for (int k0 = 0; k0 < 512; k0 += 32) {
    __syncthreads();
    *(uint4*)(&bh_lds[sn][sseg * 8]) = *(const uint4*)(bh_src + k0);
    *(uint4*)(&bl_lds[sn][sseg * 8]) = *(const uint4*)(bl_src + k0);
    __syncthreads();

    float4 xa = *(const float4*)(ax + k0);
    float4 xb = *(const float4*)(ax + k0 + 4);
    bf16x8 a_hi, a_lo;
#pragma unroll
    for (int j = 0; j < 4; ++j) {
      ushort h, l;
      split2(((const float*)&xa)[j], h, l);
      ((short*)&a_hi)[j] = (short)h; ((short*)&a_lo)[j] = (short)l;
      split2(((const float*)&xb)[j], h, l);
      ((short*)&a_hi)[4 + j] = (short)h; ((short*)&a_lo)[4 + j] = (short)l;
    }
#pragma unroll
    for (int ct = 0; ct < 4; ++ct) {
      bf16x8 bh = *(const bf16x8*)(&bh_lds[ct * 16 + col16][quad * 8]);
      bf16x8 bl = *(const bf16x8*)(&bl_lds[ct * 16 + col16][quad * 8]);
      acc[ct] = MFMA16(a_hi, bh, acc[ct]);
      acc[ct] = MFMA16(a_hi, bl, acc[ct]);
      acc[ct] = MFMA16(a_lo, bh, acc[ct]);
    }
  }

  // epilogue: permute into [bh][n][d]; sect uniform per block
  const int bhd = tmb >> 2;              // head-row  (row / 256)
  const int a0  = (tmb & 3) * 64;        // a = row % 256 base
  const int sect = tn % 3;               // 0=q 1=k 2=v
  const int s    = tn / 3;               // n & 7
#pragma unroll
  for (int ct = 0; ct < 4; ++ct) {
    const int c = ct * 16 + col16;       // d
    const float bval = bqkv[tn * 64 + c];
#pragma unroll
    for (int r = 0; r < 4; ++r) {
      const int a = a0 + w * 16 + quad * 4 + r;
      const int n = 8 * a + s;
      const size_t idx = ((size_t)bhd * 2048 + n) * 64 + c;
      const float val = acc[ct][r] + bval;
      if (sect == 0)      { ushort h, l; split2(val, h, l); q_hi[idx] = h; q_lo[idx] = l; }
      else if (sect == 1) { ushort h, l; split2(val, h, l); k_hi[idx] = h; k_lo[idx] = l; }
      else                { v_arr[idx] = f2bf_rne(val); }
    }
  }
}

// ---------------------------------------------------------------------------
// K2: flash attention. Block = 256 thr (4 waves), one (b,h) x 64-query tile.
// Q,K hi/lo -> 3-term split S MFMA; V, P plain bf16. Grid = 32*32 = 1024.
// ---------------------------------------------------------------------------
__global__ __launch_bounds__(256) void attn_k(
    const ushort* __restrict__ q_hi, const ushort* __restrict__ q_lo,
    const ushort* __restrict__ k_hi, const ushort* __restrict__ k_lo,
    const ushort* __restrict__ v_arr, ushort* __restrict__ y)
{
  const int qt  = blockIdx.x & 31;
  const int bh  = blockIdx.x >> 5;
  const int tid = threadIdx.x, lane = tid & 63, w = tid >> 6;
  const int col16 = lane & 15, quad = lane >> 4;

  __shared__ short qh_lds[64][72], ql_lds[64][72];
  __shared__ short kh_lds[64][72], kl_lds[64][72];
  __shared__ short vt_lds[64][72];          // transposed: vt[d][key]
  __shared__ short p_lds [4][16][72];       // per-wave P (C-layout -> A-layout)

  const size_t base = (size_t)bh * 2048 * 64;
  const int qbase = qt * 64;

  for (int i = tid; i < 512; i += 256) {
    const int qi = i >> 3, seg = i & 7;
    const size_t off = base + (size_t)(qbase + qi) * 64 + seg * 8;
    *(uint4*)(&qh_lds[qi][seg * 8]) = *(const uint4*)(q_hi + off);
    *(uint4*)(&ql_lds[qi][seg * 8]) = *(const uint4*)(q_lo + off);
  }

  f32x4 oacc[4];
#pragma unroll
  for (int ct = 0; ct < 4; ++ct) oacc[ct] = (f32x4){0.f, 0.f, 0.f, 0.f};
  float m_r[4], l_r[4];
#pragma unroll
  for (int r = 0; r < 4; ++r) { m_r[r] = -INFINITY; l_r[r] = 0.f; }

  for (int c = 0; c < 32; ++c) {
    __syncthreads();   // protects k/v overwrite; first iter also covers q staging
    for (int i = tid; i < 512; i += 256) {
      const int ki = i >> 3, seg = i & 7;
      const size_t off = base + (size_t)(c * 64 + ki) * 64 + seg * 8;
      *(uint4*)(&kh_lds[ki][seg * 8]) = *(const uint4*)(k_hi + off);
      *(uint4*)(&kl_lds[ki][seg * 8]) = *(const uint4*)(k_lo + off);
      uint4 vv = *(const uint4*)(v_arr + off);
      const ushort* pv = (const ushort*)&vv;
#pragma unroll
      for (int j = 0; j < 8; ++j) vt_lds[seg * 8 + j][ki] = pv[j];
    }
    __syncthreads();

    f32x4 sacc[4];
#pragma unroll
    for (int ct = 0; ct < 4; ++ct) sacc[ct] = (f32x4){0.f, 0.f, 0.f, 0.f};
#pragma unroll
    for (int ks = 0; ks < 2; ++ks) {
      bf16x8 qh = *(const bf16x8*)(&qh_lds[w * 16 + col16][ks * 32 + quad * 8]);
      bf16x8 ql = *(const bf16x8*)(&ql_lds[w * 16 + col16][ks * 32 + quad * 8]);
#pragma unroll
      for (int ct = 0; ct < 4; ++ct) {
        bf16x8 kh = *(const bf16x8*)(&kh_lds[ct * 16 + col16][ks * 32 + quad * 8]);
        bf16x8 kl = *(const bf16x8*)(&kl_lds[ct * 16 + col16][ks * 32 + quad * 8]);
        sacc[ct] = MFMA16(qh, kh, sacc[ct]);
        sacc[ct] = MFMA16(qh, kl, sacc[ct]);
        sacc[ct] = MFMA16(ql, kh, sacc[ct]);
      }
    }

#pragma unroll
    for (int r = 0; r < 4; ++r) {
      float mx = -INFINITY;
#pragma unroll
      for (int ct = 0; ct < 4; ++ct) mx = fmaxf(mx, sacc[ct][r] * 8.0f);
#pragma unroll
      for (int off = 1; off < 16; off <<= 1) mx = fmaxf(mx, __shfl_xor(mx, off, 64));
      const float mnew  = fmaxf(m_r[r], mx);
      const float alpha = __expf(m_r[r] - mnew);
      float psum = 0.f;
#pragma unroll
      for (int ct = 0; ct < 4; ++ct) {
        const float p = __expf(sacc[ct][r] * 8.0f - mnew);
        const ushort ph = f2bf_rne(p);
        psum += bf2f(ph);                  // numerator/denominator consistent
        p_lds[w][quad * 4 + r][ct * 16 + col16] = (short)ph;
      }
#pragma unroll
      for (int off = 1; off < 16; off <<= 1) psum += __shfl_xor(psum, off, 64);
      l_r[r] = l_r[r] * alpha + psum;
      m_r[r] = mnew;
#pragma unroll
      for (int ct = 0; ct < 4; ++ct) oacc[ct][r] *= alpha;
    }

#pragma unroll
    for (int ks = 0; ks < 2; ++ks) {
      bf16x8 apf = *(const bf16x8*)(&p_lds[w][col16][ks * 32 + quad * 8]);
#pragma unroll
      for (int ct = 0; ct < 4; ++ct) {
        bf16x8 bv = *(const bf16x8*)(&vt_lds[ct * 16 + col16][ks * 32 + quad * 8]);
        oacc[ct] = MFMA16(apf, bv, oacc[ct]);
      }
    }
  }

  // epilogue: y[b,h,n,d] -> yws[bh*256 + (n>>3)][(n&7)*64 + d]
#pragma unroll
  for (int r = 0; r < 4; ++r) {
    const float inv = 1.f / l_r[r];
    const int n = qbase + w * 16 + quad * 4 + r;
    const size_t orow = ((size_t)bh * 256 + (n >> 3)) * 512 + (n & 7) * 64;
#pragma unroll
    for (int ct = 0; ct < 4; ++ct)
      y[orow + ct * 16 + col16] = f2bf_rne(oacc[ct][r] * inv);
  }
}

// ---------------------------------------------------------------------------
// K3: out = yws @ Wo + bo (plain bf16 MFMA, f32 out). 64x64 tiles, grid 1024.
// ---------------------------------------------------------------------------
__global__ __launch_bounds__(256) void out_gemm_k(
    const ushort* __restrict__ y, const ushort* __restrict__ woT,
    const float* __restrict__ bo, float* __restrict__ out)
{
  const int tmb = blockIdx.x >> 3;
  const int tn  = blockIdx.x & 7;
  const int tid = threadIdx.x, lane = tid & 63, w = tid >> 6;
  const int col16 = lane & 15, quad = lane >> 4;

  __shared__ short b_lds[64][40];

  const int sn = tid >> 2, sseg = tid & 3;
  const ushort* b_src = woT + ((size_t)(tn * 64 + sn)) * 512 + sseg * 8;

  const int arow = tmb * 64 + w * 16 + col16;
  const ushort* ap = y + (size_t)arow * 512 + quad * 8;

  f32x4 acc[4];
#pragma unroll
  for (int ct = 0; ct < 4; ++ct) acc[ct] = (f32x4){0.f, 0.f, 0.f, 0.f};

  for (int k0 = 0; k0 < 512; k0 += 32) {
    __syncthreads();
    *(uint4*)(&b_lds[sn][sseg * 8]) = *(const uint4*)(b_src + k0);
    __syncthreads();
    bf16x8 af = *(const bf16x8*)(ap + k0);
#pragma unroll
    for (int ct = 0; ct < 4; ++ct) {
      bf16x8 bfr = *(const bf16x8*)(&b_lds[ct * 16 + col16][quad * 8]);
      acc[ct] = MFMA16(af, bfr, acc[ct]);
    }
  }
#pragma unroll
  for (int ct = 0; ct < 4; ++ct) {
    const int col = tn * 64 + ct * 16 + col16;
    const float bval = bo[col];
#pragma unroll
    for (int r = 0; r < 4; ++r) {
      const int row = tmb * 64 + w * 16 + quad * 4 + r;
      out[(size_t)row * 512 + col] = acc[ct][r] + bval;
    }
  }
}

// ---------------------------------------------------------------------------
extern "C" void kernel_launch(void* const* d_in, const int* in_sizes, int n_in,
                              void* d_out, int out_size, void* d_ws, size_t ws_size,
                              hipStream_t stream)
{
  const float* x    = (const float*)d_in[0];   // (4,2048,512)
  const float* Wqkv = (const float*)d_in[1];   // (512,1536)
  const float* bqkv = (const float*)d_in[2];   // (1536,)
  const float* Wo   = (const float*)d_in[3];   // (512,512)
  const float* bo   = (const float*)d_in[4];   // (512,)
  float* out = (float*)d_out;                  // (4,2048,512) f32

  // ws layout (ushort elements), total ~51.5 MiB:
  ushort* wT_hi = (ushort*)d_ws;                    //  786432 (1.5 MiB)
  ushort* wT_lo = wT_hi + 786432;                   //  786432
  ushort* woT   = wT_lo + 786432;                   //  262144 (0.5 MiB)
  ushort* q_hi  = woT   + 262144;                   // 4194304 (8 MiB)
  ushort* q_lo  = q_hi  + 4194304;
  ushort* k_hi  = q_lo  + 4194304;
  ushort* k_lo  = k_hi  + 4194304;
  ushort* v_arr = k_lo  + 4194304;
  ushort* y     = v_arr + 4194304;

  cvtw_k<<<4096, 256, 0, stream>>>(Wqkv, Wo, wT_hi, wT_lo, woT);
  qkv_gemm_k<<<3072, 256, 0, stream>>>(x, wT_hi, wT_lo, bqkv,
                                       q_hi, q_lo, k_hi, k_lo, v_arr);
  attn_k<<<1024, 256, 0, stream>>>(q_hi, q_lo, k_hi, k_lo, v_arr, y);
  out_gemm_k<<<1024, 256, 0, stream>>>(y, woT, bo, out);
}